// Round 5
// baseline (542.020 us; speedup 1.0000x reference)
//
#include <hip/hip_runtime.h>
#include <hip/hip_bf16.h>

#define NNODES 100000
#define NEDGES 1600000
#define IND 128
#define HD 64
#define OUTD 2
#define NG 64
#define SCAN_CHUNK 1024
#define BINSHIFT 9
#define BINSZ 512            // nodes per bin
#define PB 256               // partition blocks

static __device__ __forceinline__ unsigned short f2bf(float f) {
    __hip_bfloat16 h = __float2bfloat16(f);
    return *(unsigned short*)&h;
}
static __device__ __forceinline__ float bf2f(unsigned short u) {
    __hip_bfloat16 h = *(__hip_bfloat16*)&u;
    return __bfloat162float(h);
}

// ============ binned CSR build ============
// A: per-block bin histogram (LDS), no global atomics.
__global__ __launch_bounds__(256) void binA_kernel(const int* __restrict__ dst,
                                                   int* __restrict__ bbc,
                                                   int E, int nbins) {
    __shared__ int lh[256];
    lh[threadIdx.x] = 0;
    __syncthreads();
    int ebpb = (E + PB - 1) / PB;
    int e0 = blockIdx.x * ebpb;
    int e1 = min(e0 + ebpb, E);
    for (int e = e0 + threadIdx.x; e < e1; e += 256)
        atomicAdd(&lh[dst[e] >> BINSHIFT], 1);
    __syncthreads();
    bbc[blockIdx.x * 256 + threadIdx.x] = lh[threadIdx.x];
}

// B1: per-bin exclusive scan across the 256 partition blocks.
__global__ __launch_bounds__(256) void binB1_kernel(int* __restrict__ bbc,
                                                    int* __restrict__ binTotal,
                                                    int* __restrict__ binStart) {
    __shared__ int ws[4];
    int b = blockIdx.x;
    int t = threadIdx.x, lane = t & 63, wv = t >> 6;
    int v = bbc[t * 256 + b];
    int sc = v;
#pragma unroll
    for (int d = 1; d < 64; d <<= 1) { int u = __shfl_up(sc, d, 64); if (lane >= d) sc += u; }
    if (lane == 63) ws[wv] = sc;
    __syncthreads();
    int add = 0;
    for (int w = 0; w < wv; w++) add += ws[w];
    bbc[t * 256 + b] = sc - v + add;
    if (t == 255) { int tot = sc + add; binTotal[b] = tot; binStart[b] = tot; }
}

// B2 / generic 1-wave exclusive scan (also used for rowptr chunk sums)
__global__ __launch_bounds__(64) void scan_bsums_kernel(int* __restrict__ bsum, int nchunks) {
    int lane = threadIdx.x;
    int cpl = (nchunks + 63) / 64;     // <= 8 assumed
    int vals[8];
    int i0 = lane * cpl;
    int t = 0;
    for (int k = 0; k < cpl; k++) {
        int i = i0 + k;
        vals[k] = (i < nchunks) ? bsum[i] : 0;
        t += vals[k];
    }
    int sc = t;
#pragma unroll
    for (int d = 1; d < 64; d <<= 1) { int v = __shfl_up(sc, d, 64); if (lane >= d) sc += v; }
    int ex = sc - t;
    for (int k = 0; k < cpl; k++) {
        int i = i0 + k;
        if (i < nchunks) bsum[i] = ex;
        ex += vals[k];
    }
}

// C: partition edges into bin-contiguous packed records. No global atomics.
// record = (doff << 17) | src   (src < 2^17, doff < 2^9)
__global__ __launch_bounds__(256) void binC_kernel(const int* __restrict__ src,
                                                   const int* __restrict__ dst,
                                                   const int* __restrict__ bbc,
                                                   const int* __restrict__ binStart,
                                                   unsigned int* __restrict__ binned,
                                                   int E, int nbins) {
    __shared__ int cur[256];
    int t = threadIdx.x;
    if (t < nbins) cur[t] = binStart[t] + bbc[blockIdx.x * 256 + t];
    __syncthreads();
    int ebpb = (E + PB - 1) / PB;
    int e0 = blockIdx.x * ebpb;
    int e1 = min(e0 + ebpb, E);
    for (int e = e0 + t; e < e1; e += 256) {
        int d = dst[e];
        int b = d >> BINSHIFT;
        int p = atomicAdd(&cur[b], 1);
        binned[p] = ((unsigned int)(d & (BINSZ - 1)) << 17) | (unsigned int)src[e];
    }
}

// H: per-bin node degree histogram (LDS) -> hist + dinv.
__global__ __launch_bounds__(256) void binH_kernel(const unsigned int* __restrict__ binned,
                                                   const int* __restrict__ binStart,
                                                   const int* __restrict__ binTotal,
                                                   int* __restrict__ hist,
                                                   float* __restrict__ dinv, int n) {
    __shared__ int dh[BINSZ];
    int b = blockIdx.x;
    int t = threadIdx.x;
    dh[t] = 0; dh[t + 256] = 0;
    __syncthreads();
    int s0 = binStart[b], cnt = binTotal[b];
    for (int i = t; i < cnt; i += 256)
        atomicAdd(&dh[binned[s0 + i] >> 17], 1);
    __syncthreads();
#pragma unroll
    for (int r = 0; r < 2; r++) {
        int i = t + r * 256;
        int node = (b << BINSHIFT) + i;
        if (node < n) {
            int dg = dh[i];
            hist[node] = dg;
            dinv[node] = 1.0f / sqrtf((float)(dg + 1));
        }
    }
}

// ---------------- rowptr scan over hist (3 phases) ----------------
__global__ __launch_bounds__(256) void scan_sum_kernel(const int* __restrict__ hist,
                                                       int* __restrict__ bsum, int n) {
    __shared__ int wsums[4];
    int lane = threadIdx.x & 63, wv = threadIdx.x >> 6;
    int i0 = blockIdx.x * SCAN_CHUNK + threadIdx.x * 4;
    int t = 0;
#pragma unroll
    for (int k = 0; k < 4; k++) { int i = i0 + k; if (i < n) t += hist[i]; }
#pragma unroll
    for (int d = 32; d > 0; d >>= 1) t += __shfl_down(t, d, 64);
    if (lane == 0) wsums[wv] = t;
    __syncthreads();
    if (threadIdx.x == 0) bsum[blockIdx.x] = wsums[0] + wsums[1] + wsums[2] + wsums[3];
}

__global__ __launch_bounds__(256) void scan_write_kernel(const int* __restrict__ hist,
                                                         const int* __restrict__ bofs,
                                                         int* __restrict__ rowptr,
                                                         int n, int total) {
    __shared__ int wsum[4];
    int lane = threadIdx.x & 63, wv = threadIdx.x >> 6;
    int i0 = blockIdx.x * SCAN_CHUNK + threadIdx.x * 4;
    int h[4]; int t = 0;
#pragma unroll
    for (int k = 0; k < 4; k++) { int i = i0 + k; h[k] = (i < n) ? hist[i] : 0; t += h[k]; }
    int sc = t;
#pragma unroll
    for (int d = 1; d < 64; d <<= 1) { int v = __shfl_up(sc, d, 64); if (lane >= d) sc += v; }
    if (lane == 63) wsum[wv] = sc;
    __syncthreads();
    int wofs = 0;
    for (int w = 0; w < wv; w++) wofs += wsum[w];
    int ex = (sc - t) + wofs + bofs[blockIdx.x];
#pragma unroll
    for (int k = 0; k < 4; k++) { int i = i0 + k; if (i < n) rowptr[i] = ex; ex += h[k]; }
    if (blockIdx.x == 0 && threadIdx.x == 0) rowptr[n] = total;
}

// D: per-bin CSR scatter. LDS countdown + LDS rowptr slice.
__global__ __launch_bounds__(256) void binD_kernel(const unsigned int* __restrict__ binned,
                                                   const int* __restrict__ binStart,
                                                   const int* __restrict__ binTotal,
                                                   const int* __restrict__ hist,
                                                   const int* __restrict__ rowptr,
                                                   int* __restrict__ ssrc, int n) {
    __shared__ int cntL[BINSZ];
    __shared__ int rpL[BINSZ];
    int b = blockIdx.x;
    int t = threadIdx.x;
#pragma unroll
    for (int r = 0; r < 2; r++) {
        int i = t + r * 256;
        int node = (b << BINSHIFT) + i;
        if (node < n) { cntL[i] = hist[node]; rpL[i] = rowptr[node]; }
    }
    __syncthreads();
    int s0 = binStart[b], cnt = binTotal[b];
    for (int i = t; i < cnt; i += 256) {
        unsigned int rec = binned[s0 + i];
        int doff = rec >> 17;
        int s = rec & 0x1FFFF;
        int idx = atomicSub(&cntL[doff], 1) - 1;
        ssrc[rpL[doff] + idx] = s;
    }
}

// ---------------- dense matmul: Tb[n, 0..63] = bf16( X[n, :K] @ W[K, 64] ) --
// thread tile = 2 nodes x 8 features; 64 nodes/block -> grid ~1563 for high
// occupancy (round-4 mm was grid-limited at 25% occupancy).
template <int K>
__global__ __launch_bounds__(256) void mm_kernel(const float* __restrict__ X,
                                                 const float* __restrict__ W,
                                                 unsigned short* __restrict__ Tb, int nn) {
    const int lane   = threadIdx.x & 63;
    const int wv     = threadIdx.x >> 6;
    const int feat_t = lane & 7;          // 8 feature groups of 8
    const int node_t = lane >> 3;         // 8 node groups of 2 -> 16 nodes/wave
    const int j0 = feat_t * 8;
    const int nb = blockIdx.x * 64 + wv * 16 + node_t * 2;
    if (blockIdx.x * 64 >= nn) return;

    const int nclamp = nn - 1;
    const float* xr0 = X + (size_t)min(nb + 0, nclamp) * K;
    const float* xr1 = X + (size_t)min(nb + 1, nclamp) * K;

    float acc[2][8];
#pragma unroll
    for (int u = 0; u < 2; u++)
#pragma unroll
        for (int v = 0; v < 8; v++) acc[u][v] = 0.f;

#pragma unroll 2
    for (int k = 0; k < K; k += 4) {
        float4 x0 = *(const float4*)(xr0 + k);
        float4 x1 = *(const float4*)(xr1 + k);
#pragma unroll
        for (int kk = 0; kk < 4; kk++) {
            float4 wa = *(const float4*)(W + (size_t)(k + kk) * 64 + j0);
            float4 wb = *(const float4*)(W + (size_t)(k + kk) * 64 + j0 + 4);
            float xs0 = (&x0.x)[kk];
            float xs1 = (&x1.x)[kk];
            acc[0][0] += xs0 * wa.x; acc[0][1] += xs0 * wa.y;
            acc[0][2] += xs0 * wa.z; acc[0][3] += xs0 * wa.w;
            acc[0][4] += xs0 * wb.x; acc[0][5] += xs0 * wb.y;
            acc[0][6] += xs0 * wb.z; acc[0][7] += xs0 * wb.w;
            acc[1][0] += xs1 * wa.x; acc[1][1] += xs1 * wa.y;
            acc[1][2] += xs1 * wa.z; acc[1][3] += xs1 * wa.w;
            acc[1][4] += xs1 * wb.x; acc[1][5] += xs1 * wb.y;
            acc[1][6] += xs1 * wb.z; acc[1][7] += xs1 * wb.w;
        }
    }

#pragma unroll
    for (int u = 0; u < 2; u++) {
        if (nb + u < nn) {
            uint4 p;
            p.x = (unsigned int)f2bf(acc[u][0]) | ((unsigned int)f2bf(acc[u][1]) << 16);
            p.y = (unsigned int)f2bf(acc[u][2]) | ((unsigned int)f2bf(acc[u][3]) << 16);
            p.z = (unsigned int)f2bf(acc[u][4]) | ((unsigned int)f2bf(acc[u][5]) << 16);
            p.w = (unsigned int)f2bf(acc[u][6]) | ((unsigned int)f2bf(acc[u][7]) << 16);
            *(uint4*)(Tb + (size_t)(nb + u) * 64 + j0) = p;
        }
    }
}

// ---------------- pull aggregation + self loop + bias + relu ----------------
// wave per node, lane = feature. T rows are bf16 (128 B gather per edge).
__global__ __launch_bounds__(256) void agg_kernel(const unsigned short* __restrict__ Tb,
                                                  const int* __restrict__ rowptr,
                                                  const int* __restrict__ ssrc,
                                                  const float* __restrict__ dinv,
                                                  const float* __restrict__ bias,
                                                  float* __restrict__ O, int nn) {
    int wave = __builtin_amdgcn_readfirstlane((blockIdx.x * 256 + threadIdx.x) >> 6);
    int lane = threadIdx.x & 63;
    if (wave >= nn) return;
    int n = wave;
    float di = dinv[n];
    float acc = di * di * bf2f(Tb[(size_t)n * 64 + lane]);
    int rb = rowptr[n], re = rowptr[n + 1];
    int i = rb;
    for (; i + 3 < re; i += 4) {
        int s0 = ssrc[i], s1 = ssrc[i + 1], s2 = ssrc[i + 2], s3 = ssrc[i + 3];
        float w0 = di * dinv[s0];
        float w1 = di * dinv[s1];
        float w2 = di * dinv[s2];
        float w3 = di * dinv[s3];
        float v0 = bf2f(Tb[(size_t)s0 * 64 + lane]);
        float v1 = bf2f(Tb[(size_t)s1 * 64 + lane]);
        float v2 = bf2f(Tb[(size_t)s2 * 64 + lane]);
        float v3 = bf2f(Tb[(size_t)s3 * 64 + lane]);
        acc += w0 * v0;
        acc += w1 * v1;
        acc += w2 * v2;
        acc += w3 * v3;
    }
    for (; i < re; i++) {
        int s0 = ssrc[i];
        acc += di * dinv[s0] * bf2f(Tb[(size_t)s0 * 64 + lane]);
    }
    float v = acc + bias[lane];
    O[(size_t)n * 64 + lane] = v > 0.f ? v : 0.f;
}

// ---------------- mean pool: exploit sorted batch ids ----------------
__global__ __launch_bounds__(256) void pool_kernel(const float* __restrict__ H,
                                                   const int* __restrict__ batch,
                                                   float* __restrict__ pooled,
                                                   float* __restrict__ gcnt, int nn) {
    int wid = (blockIdx.x * 256 + threadIdx.x) >> 6;
    int lane = threadIdx.x & 63;
    int nwaves = (gridDim.x * 256) >> 6;
    int per = (nn + nwaves - 1) / nwaves;
    int n0 = wid * per;
    int n1 = n0 + per; if (n1 > nn) n1 = nn;
    if (n0 >= n1) return;
    int cur = batch[n0];
    float acc = 0.f, cnt = 0.f;
    for (int n = n0; n < n1; ++n) {
        int g = batch[n];
        if (g != cur) {
            atomicAdd(&pooled[cur * 64 + lane], acc);
            if (lane == 0) atomicAdd(&gcnt[cur], cnt);
            acc = 0.f; cnt = 0.f; cur = g;
        }
        acc += H[(size_t)n * 64 + lane];
        cnt += 1.f;
    }
    atomicAdd(&pooled[cur * 64 + lane], acc);
    if (lane == 0) atomicAdd(&gcnt[cur], cnt);
}

// ---------------- MLP head (single block) ----------------
__global__ __launch_bounds__(256) void head_kernel(const float* __restrict__ pooled,
                                                   const float* __restrict__ gcnt,
                                                   const float* __restrict__ Wm1,
                                                   const float* __restrict__ bm1,
                                                   const float* __restrict__ Wm2,
                                                   const float* __restrict__ bm2,
                                                   float* __restrict__ out) {
    __shared__ float P[NG * 64];
    __shared__ float Z[NG * 64];
    int tid = threadIdx.x;
    for (int i = tid; i < NG * 64; i += 256) {
        int g = i >> 6;
        float c = gcnt[g];
        c = c > 1.f ? c : 1.f;
        P[i] = pooled[i] / c;
    }
    __syncthreads();
    for (int i = tid; i < NG * 64; i += 256) {
        int g = i >> 6, j = i & 63;
        float a = bm1[j];
#pragma unroll 8
        for (int k = 0; k < 64; ++k) a += P[g * 64 + k] * Wm1[k * 64 + j];
        Z[i] = a > 0.f ? a : 0.f;
    }
    __syncthreads();
    for (int i = tid; i < NG * OUTD; i += 256) {
        int g = i / OUTD, o = i % OUTD;
        float a = bm2[o];
#pragma unroll 8
        for (int k = 0; k < 64; ++k) a += Z[g * 64 + k] * Wm2[k * OUTD + o];
        out[i] = a;
    }
}

extern "C" void kernel_launch(void* const* d_in, const int* in_sizes, int n_in,
                              void* d_out, int out_size, void* d_ws, size_t ws_size,
                              hipStream_t stream) {
    const float* x    = (const float*)d_in[0];
    const int*  edge  = (const int*)d_in[1];
    const int*  batch = (const int*)d_in[2];
    const float* W1 = (const float*)d_in[3];
    const float* b1 = (const float*)d_in[4];
    const float* W2 = (const float*)d_in[5];
    const float* b2 = (const float*)d_in[6];
    const float* W3 = (const float*)d_in[7];
    const float* b3 = (const float*)d_in[8];
    const float* Wm1 = (const float*)d_in[9];
    const float* bm1 = (const float*)d_in[10];
    const float* Wm2 = (const float*)d_in[11];
    const float* bm2 = (const float*)d_in[12];

    const int N_ = in_sizes[2];           // 100000 (batch length)
    const int E_ = in_sizes[1] / 2;       // 1600000
    const int* src = edge;
    const int* dst = edge + E_;
    const int nbins = (N_ + BINSZ - 1) >> BINSHIFT;   // 196

    // workspace carve (256 B aligned)
    char* w = (char*)d_ws;
    auto alloc = [&](size_t bytes) -> void* {
        void* p = (void*)w;
        w += (bytes + 255) & ~(size_t)255;
        return p;
    };
    float* dinv   = (float*)alloc((size_t)N_ * 4);
    int*   hist   = (int*)alloc((size_t)N_ * 4);
    int*   rowptr = (int*)alloc((size_t)(N_ + 1) * 4);
    int*   bsum   = (int*)alloc(512 * 4);
    int*   bbc    = (int*)alloc((size_t)256 * 256 * 4);
    int*   binTotal = (int*)alloc(256 * 4);
    int*   binStart = (int*)alloc(256 * 4);
    int*   ssrc   = (int*)alloc((size_t)E_ * 4);
    unsigned short* Tb = (unsigned short*)alloc((size_t)N_ * 64 * 2);
    float* hB     = (float*)alloc((size_t)N_ * 64 * 4);
    float* pooled = (float*)alloc((size_t)(NG * 64 + NG) * 4);
    float* gcnt   = pooled + NG * 64;
    unsigned int* binned = (unsigned int*)hB;   // alias: consumed before agg writes hB

    const int nchunks = (N_ + SCAN_CHUNK - 1) / SCAN_CHUNK;

    hipMemsetAsync(pooled, 0, (size_t)(NG * 64 + NG) * 4, stream);

    // ---- binned CSR build ----
    binA_kernel<<<PB, 256, 0, stream>>>(dst, bbc, E_, nbins);
    binB1_kernel<<<nbins, 256, 0, stream>>>(bbc, binTotal, binStart);
    scan_bsums_kernel<<<1, 64, 0, stream>>>(binStart, nbins);
    binC_kernel<<<PB, 256, 0, stream>>>(src, dst, bbc, binStart, binned, E_, nbins);
    binH_kernel<<<nbins, 256, 0, stream>>>(binned, binStart, binTotal, hist, dinv, N_);
    scan_sum_kernel<<<nchunks, 256, 0, stream>>>(hist, bsum, N_);
    scan_bsums_kernel<<<1, 64, 0, stream>>>(bsum, nchunks);
    scan_write_kernel<<<nchunks, 256, 0, stream>>>(hist, bsum, rowptr, N_, E_);
    binD_kernel<<<nbins, 256, 0, stream>>>(binned, binStart, binTotal, hist, rowptr, ssrc, N_);

    const int mmblk = (N_ + 63) / 64;             // 64 nodes per block
    const int aggblk = (N_ + 3) / 4;              // 4 waves (nodes) per block

    // layer 1: t = x @ W1 ; h = agg(t) + b1, relu
    mm_kernel<IND><<<mmblk, 256, 0, stream>>>(x, W1, Tb, N_);
    agg_kernel<<<aggblk, 256, 0, stream>>>(Tb, rowptr, ssrc, dinv, b1, hB, N_);
    // layer 2
    mm_kernel<HD><<<mmblk, 256, 0, stream>>>(hB, W2, Tb, N_);
    agg_kernel<<<aggblk, 256, 0, stream>>>(Tb, rowptr, ssrc, dinv, b2, hB, N_);
    // layer 3
    mm_kernel<HD><<<mmblk, 256, 0, stream>>>(hB, W3, Tb, N_);
    agg_kernel<<<aggblk, 256, 0, stream>>>(Tb, rowptr, ssrc, dinv, b3, hB, N_);

    // pool + head
    pool_kernel<<<256, 256, 0, stream>>>(hB, batch, pooled, gcnt, N_);
    head_kernel<<<1, 256, 0, stream>>>(pooled, gcnt, Wm1, bm1, Wm2, bm2, (float*)d_out);
}

// Round 6
// 455.778 us; speedup vs baseline: 1.1892x; 1.1892x over previous
//
#include <hip/hip_runtime.h>
#include <hip/hip_bf16.h>

#define NNODES 100000
#define NEDGES 1600000
#define IND 128
#define HD 64
#define OUTD 2
#define NG 64
#define SCAN_CHUNK 1024
#define BINSHIFT 9
#define BINSZ 512            // nodes per bin
#define PB 256               // partition blocks

typedef __attribute__((ext_vector_type(8))) short short8v;
typedef __attribute__((ext_vector_type(4))) float floatx4;

static __device__ __forceinline__ unsigned short f2bf(float f) {
    __hip_bfloat16 h = __float2bfloat16(f);
    return *(unsigned short*)&h;
}
static __device__ __forceinline__ float bf2f(unsigned short u) {
    __hip_bfloat16 h = *(__hip_bfloat16*)&u;
    return __bfloat162float(h);
}

// ============ binned CSR build ============
__global__ __launch_bounds__(256) void binA_kernel(const int* __restrict__ dst,
                                                   int* __restrict__ bbc,
                                                   int E, int nbins) {
    __shared__ int lh[256];
    lh[threadIdx.x] = 0;
    __syncthreads();
    int ebpb = (E + PB - 1) / PB;
    int e0 = blockIdx.x * ebpb;
    int e1 = min(e0 + ebpb, E);
    for (int e = e0 + threadIdx.x; e < e1; e += 256)
        atomicAdd(&lh[dst[e] >> BINSHIFT], 1);
    __syncthreads();
    bbc[blockIdx.x * 256 + threadIdx.x] = lh[threadIdx.x];
}

__global__ __launch_bounds__(256) void binB1_kernel(int* __restrict__ bbc,
                                                    int* __restrict__ binTotal,
                                                    int* __restrict__ binStart) {
    __shared__ int ws[4];
    int b = blockIdx.x;
    int t = threadIdx.x, lane = t & 63, wv = t >> 6;
    int v = bbc[t * 256 + b];
    int sc = v;
#pragma unroll
    for (int d = 1; d < 64; d <<= 1) { int u = __shfl_up(sc, d, 64); if (lane >= d) sc += u; }
    if (lane == 63) ws[wv] = sc;
    __syncthreads();
    int add = 0;
    for (int w = 0; w < wv; w++) add += ws[w];
    bbc[t * 256 + b] = sc - v + add;
    if (t == 255) { int tot = sc + add; binTotal[b] = tot; binStart[b] = tot; }
}

__global__ __launch_bounds__(64) void scan_bsums_kernel(int* __restrict__ bsum, int nchunks) {
    int lane = threadIdx.x;
    int cpl = (nchunks + 63) / 64;     // <= 8 assumed
    int vals[8];
    int i0 = lane * cpl;
    int t = 0;
    for (int k = 0; k < cpl; k++) {
        int i = i0 + k;
        vals[k] = (i < nchunks) ? bsum[i] : 0;
        t += vals[k];
    }
    int sc = t;
#pragma unroll
    for (int d = 1; d < 64; d <<= 1) { int v = __shfl_up(sc, d, 64); if (lane >= d) sc += v; }
    int ex = sc - t;
    for (int k = 0; k < cpl; k++) {
        int i = i0 + k;
        if (i < nchunks) bsum[i] = ex;
        ex += vals[k];
    }
}

// record = (doff << 17) | src   (src < 2^17, doff < 2^9)
__global__ __launch_bounds__(256) void binC_kernel(const int* __restrict__ src,
                                                   const int* __restrict__ dst,
                                                   const int* __restrict__ bbc,
                                                   const int* __restrict__ binStart,
                                                   unsigned int* __restrict__ binned,
                                                   int E, int nbins) {
    __shared__ int cur[256];
    int t = threadIdx.x;
    if (t < nbins) cur[t] = binStart[t] + bbc[blockIdx.x * 256 + t];
    __syncthreads();
    int ebpb = (E + PB - 1) / PB;
    int e0 = blockIdx.x * ebpb;
    int e1 = min(e0 + ebpb, E);
    for (int e = e0 + t; e < e1; e += 256) {
        int d = dst[e];
        int b = d >> BINSHIFT;
        int p = atomicAdd(&cur[b], 1);
        binned[p] = ((unsigned int)(d & (BINSZ - 1)) << 17) | (unsigned int)src[e];
    }
}

__global__ __launch_bounds__(256) void binH_kernel(const unsigned int* __restrict__ binned,
                                                   const int* __restrict__ binStart,
                                                   const int* __restrict__ binTotal,
                                                   int* __restrict__ hist,
                                                   float* __restrict__ dinv, int n) {
    __shared__ int dh[BINSZ];
    int b = blockIdx.x;
    int t = threadIdx.x;
    dh[t] = 0; dh[t + 256] = 0;
    __syncthreads();
    int s0 = binStart[b], cnt = binTotal[b];
    for (int i = t; i < cnt; i += 256)
        atomicAdd(&dh[binned[s0 + i] >> 17], 1);
    __syncthreads();
#pragma unroll
    for (int r = 0; r < 2; r++) {
        int i = t + r * 256;
        int node = (b << BINSHIFT) + i;
        if (node < n) {
            int dg = dh[i];
            hist[node] = dg;
            dinv[node] = 1.0f / sqrtf((float)(dg + 1));
        }
    }
}

__global__ __launch_bounds__(256) void scan_sum_kernel(const int* __restrict__ hist,
                                                       int* __restrict__ bsum, int n) {
    __shared__ int wsums[4];
    int lane = threadIdx.x & 63, wv = threadIdx.x >> 6;
    int i0 = blockIdx.x * SCAN_CHUNK + threadIdx.x * 4;
    int t = 0;
#pragma unroll
    for (int k = 0; k < 4; k++) { int i = i0 + k; if (i < n) t += hist[i]; }
#pragma unroll
    for (int d = 32; d > 0; d >>= 1) t += __shfl_down(t, d, 64);
    if (lane == 0) wsums[wv] = t;
    __syncthreads();
    if (threadIdx.x == 0) bsum[blockIdx.x] = wsums[0] + wsums[1] + wsums[2] + wsums[3];
}

__global__ __launch_bounds__(256) void scan_write_kernel(const int* __restrict__ hist,
                                                         const int* __restrict__ bofs,
                                                         int* __restrict__ rowptr,
                                                         int n, int total) {
    __shared__ int wsum[4];
    int lane = threadIdx.x & 63, wv = threadIdx.x >> 6;
    int i0 = blockIdx.x * SCAN_CHUNK + threadIdx.x * 4;
    int h[4]; int t = 0;
#pragma unroll
    for (int k = 0; k < 4; k++) { int i = i0 + k; h[k] = (i < n) ? hist[i] : 0; t += h[k]; }
    int sc = t;
#pragma unroll
    for (int d = 1; d < 64; d <<= 1) { int v = __shfl_up(sc, d, 64); if (lane >= d) sc += v; }
    if (lane == 63) wsum[wv] = sc;
    __syncthreads();
    int wofs = 0;
    for (int w = 0; w < wv; w++) wofs += wsum[w];
    int ex = (sc - t) + wofs + bofs[blockIdx.x];
#pragma unroll
    for (int k = 0; k < 4; k++) { int i = i0 + k; if (i < n) rowptr[i] = ex; ex += h[k]; }
    if (blockIdx.x == 0 && threadIdx.x == 0) rowptr[n] = total;
}

__global__ __launch_bounds__(256) void binD_kernel(const unsigned int* __restrict__ binned,
                                                   const int* __restrict__ binStart,
                                                   const int* __restrict__ binTotal,
                                                   const int* __restrict__ hist,
                                                   const int* __restrict__ rowptr,
                                                   int* __restrict__ ssrc, int n) {
    __shared__ int cntL[BINSZ];
    __shared__ int rpL[BINSZ];
    int b = blockIdx.x;
    int t = threadIdx.x;
#pragma unroll
    for (int r = 0; r < 2; r++) {
        int i = t + r * 256;
        int node = (b << BINSHIFT) + i;
        if (node < n) { cntL[i] = hist[node]; rpL[i] = rowptr[node]; }
    }
    __syncthreads();
    int s0 = binStart[b], cnt = binTotal[b];
    for (int i = t; i < cnt; i += 256) {
        unsigned int rec = binned[s0 + i];
        int doff = rec >> 17;
        int s = rec & 0x1FFFF;
        int idx = atomicSub(&cntL[doff], 1) - 1;
        ssrc[rpL[doff] + idx] = s;
    }
}

// ---------------- W transpose + bf16 convert: WT[n][k] = bf16(W[k][n]) -----
__global__ __launch_bounds__(256) void cvtWT_kernel(const float* __restrict__ W,
                                                    unsigned short* __restrict__ WT, int K) {
    int i = blockIdx.x * 256 + threadIdx.x;
    if (i < 64 * K) {
        int n = i / K, k = i - n * K;
        WT[i] = f2bf(W[k * 64 + n]);
    }
}

// ---------------- MFMA matmul: Tb[n][0..63] = bf16( X[n,:K] @ W[K,64] ) ----
// Wave = 16 nodes x 64 feats (4 accumulators of 16x16). K-step 32:
//   A-frag: A[m=lane&15][k=quad*8+j] -> one 16B load from row-major X row
//   B-frag: B[k=quad*8+j][n=lane&15] -> one 16B load from WT (bf16 W^T)
//   C/D   : col=lane&15, row=quad*4+reg  (HW-verified layouts)
template <int K, bool BF16IN>
__global__ __launch_bounds__(256) void mm_mfma_kernel(const void* __restrict__ Xv,
                                                      const unsigned short* __restrict__ WT,
                                                      unsigned short* __restrict__ Tb, int nn) {
    const int lane = threadIdx.x & 63;
    const int wv   = threadIdx.x >> 6;
    const int nb   = blockIdx.x * 64 + wv * 16;
    if (nb >= nn) return;
    const int col  = lane & 15;
    const int quad = lane >> 4;
    const int m    = min(nb + col, nn - 1);

    floatx4 acc0 = {0.f, 0.f, 0.f, 0.f};
    floatx4 acc1 = {0.f, 0.f, 0.f, 0.f};
    floatx4 acc2 = {0.f, 0.f, 0.f, 0.f};
    floatx4 acc3 = {0.f, 0.f, 0.f, 0.f};

#pragma unroll
    for (int ks = 0; ks < K; ks += 32) {
        const int k0 = ks + quad * 8;
        short8v a;
        if (BF16IN) {
            a = *(const short8v*)((const unsigned short*)Xv + (size_t)m * K + k0);
        } else {
            const float* xr = (const float*)Xv + (size_t)m * K + k0;
            float4 f0 = *(const float4*)(xr);
            float4 f1 = *(const float4*)(xr + 4);
            a[0] = (short)f2bf(f0.x); a[1] = (short)f2bf(f0.y);
            a[2] = (short)f2bf(f0.z); a[3] = (short)f2bf(f0.w);
            a[4] = (short)f2bf(f1.x); a[5] = (short)f2bf(f1.y);
            a[6] = (short)f2bf(f1.z); a[7] = (short)f2bf(f1.w);
        }
        short8v b0 = *(const short8v*)(WT + (size_t)(0  + col) * K + k0);
        short8v b1 = *(const short8v*)(WT + (size_t)(16 + col) * K + k0);
        short8v b2 = *(const short8v*)(WT + (size_t)(32 + col) * K + k0);
        short8v b3 = *(const short8v*)(WT + (size_t)(48 + col) * K + k0);
        acc0 = __builtin_amdgcn_mfma_f32_16x16x32_bf16(a, b0, acc0, 0, 0, 0);
        acc1 = __builtin_amdgcn_mfma_f32_16x16x32_bf16(a, b1, acc1, 0, 0, 0);
        acc2 = __builtin_amdgcn_mfma_f32_16x16x32_bf16(a, b2, acc2, 0, 0, 0);
        acc3 = __builtin_amdgcn_mfma_f32_16x16x32_bf16(a, b3, acc3, 0, 0, 0);
    }

#pragma unroll
    for (int r = 0; r < 4; r++) {
        int node = nb + quad * 4 + r;
        if (node < nn) {
            unsigned short* o = Tb + (size_t)node * 64 + col;
            o[0]  = f2bf(acc0[r]);
            o[16] = f2bf(acc1[r]);
            o[32] = f2bf(acc2[r]);
            o[48] = f2bf(acc3[r]);
        }
    }
}

// ---------------- pull aggregation + self loop + bias + relu (bf16 out) ----
__global__ __launch_bounds__(256) void agg_kernel(const unsigned short* __restrict__ Tb,
                                                  const int* __restrict__ rowptr,
                                                  const int* __restrict__ ssrc,
                                                  const float* __restrict__ dinv,
                                                  const float* __restrict__ bias,
                                                  unsigned short* __restrict__ Ob, int nn) {
    int wave = __builtin_amdgcn_readfirstlane((blockIdx.x * 256 + threadIdx.x) >> 6);
    int lane = threadIdx.x & 63;
    if (wave >= nn) return;
    int n = wave;
    float di = dinv[n];
    float acc = di * di * bf2f(Tb[(size_t)n * 64 + lane]);
    int rb = rowptr[n], re = rowptr[n + 1];
    int i = rb;
    for (; i + 3 < re; i += 4) {
        int s0 = ssrc[i], s1 = ssrc[i + 1], s2 = ssrc[i + 2], s3 = ssrc[i + 3];
        float w0 = di * dinv[s0];
        float w1 = di * dinv[s1];
        float w2 = di * dinv[s2];
        float w3 = di * dinv[s3];
        float v0 = bf2f(Tb[(size_t)s0 * 64 + lane]);
        float v1 = bf2f(Tb[(size_t)s1 * 64 + lane]);
        float v2 = bf2f(Tb[(size_t)s2 * 64 + lane]);
        float v3 = bf2f(Tb[(size_t)s3 * 64 + lane]);
        acc += w0 * v0;
        acc += w1 * v1;
        acc += w2 * v2;
        acc += w3 * v3;
    }
    for (; i < re; i++) {
        int s0 = ssrc[i];
        acc += di * dinv[s0] * bf2f(Tb[(size_t)s0 * 64 + lane]);
    }
    float v = acc + bias[lane];
    Ob[(size_t)n * 64 + lane] = f2bf(v > 0.f ? v : 0.f);
}

// ---------------- mean pool (bf16 input): exploit sorted batch ids ---------
__global__ __launch_bounds__(256) void pool_kernel(const unsigned short* __restrict__ Hb,
                                                   const int* __restrict__ batch,
                                                   float* __restrict__ pooled,
                                                   float* __restrict__ gcnt, int nn) {
    int wid = (blockIdx.x * 256 + threadIdx.x) >> 6;
    int lane = threadIdx.x & 63;
    int nwaves = (gridDim.x * 256) >> 6;
    int per = (nn + nwaves - 1) / nwaves;
    int n0 = wid * per;
    int n1 = n0 + per; if (n1 > nn) n1 = nn;
    if (n0 >= n1) return;
    int cur = batch[n0];
    float acc = 0.f, cnt = 0.f;
    for (int n = n0; n < n1; ++n) {
        int g = batch[n];
        if (g != cur) {
            atomicAdd(&pooled[cur * 64 + lane], acc);
            if (lane == 0) atomicAdd(&gcnt[cur], cnt);
            acc = 0.f; cnt = 0.f; cur = g;
        }
        acc += bf2f(Hb[(size_t)n * 64 + lane]);
        cnt += 1.f;
    }
    atomicAdd(&pooled[cur * 64 + lane], acc);
    if (lane == 0) atomicAdd(&gcnt[cur], cnt);
}

// ---------------- MLP head (single block) ----------------
__global__ __launch_bounds__(256) void head_kernel(const float* __restrict__ pooled,
                                                   const float* __restrict__ gcnt,
                                                   const float* __restrict__ Wm1,
                                                   const float* __restrict__ bm1,
                                                   const float* __restrict__ Wm2,
                                                   const float* __restrict__ bm2,
                                                   float* __restrict__ out) {
    __shared__ float P[NG * 64];
    __shared__ float Z[NG * 64];
    int tid = threadIdx.x;
    for (int i = tid; i < NG * 64; i += 256) {
        int g = i >> 6;
        float c = gcnt[g];
        c = c > 1.f ? c : 1.f;
        P[i] = pooled[i] / c;
    }
    __syncthreads();
    for (int i = tid; i < NG * 64; i += 256) {
        int g = i >> 6, j = i & 63;
        float a = bm1[j];
#pragma unroll 8
        for (int k = 0; k < 64; ++k) a += P[g * 64 + k] * Wm1[k * 64 + j];
        Z[i] = a > 0.f ? a : 0.f;
    }
    __syncthreads();
    for (int i = tid; i < NG * OUTD; i += 256) {
        int g = i / OUTD, o = i % OUTD;
        float a = bm2[o];
#pragma unroll 8
        for (int k = 0; k < 64; ++k) a += Z[g * 64 + k] * Wm2[k * OUTD + o];
        out[i] = a;
    }
}

extern "C" void kernel_launch(void* const* d_in, const int* in_sizes, int n_in,
                              void* d_out, int out_size, void* d_ws, size_t ws_size,
                              hipStream_t stream) {
    const float* x    = (const float*)d_in[0];
    const int*  edge  = (const int*)d_in[1];
    const int*  batch = (const int*)d_in[2];
    const float* W1 = (const float*)d_in[3];
    const float* b1 = (const float*)d_in[4];
    const float* W2 = (const float*)d_in[5];
    const float* b2 = (const float*)d_in[6];
    const float* W3 = (const float*)d_in[7];
    const float* b3 = (const float*)d_in[8];
    const float* Wm1 = (const float*)d_in[9];
    const float* bm1 = (const float*)d_in[10];
    const float* Wm2 = (const float*)d_in[11];
    const float* bm2 = (const float*)d_in[12];

    const int N_ = in_sizes[2];           // 100000 (batch length)
    const int E_ = in_sizes[1] / 2;       // 1600000
    const int* src = edge;
    const int* dst = edge + E_;
    const int nbins = (N_ + BINSZ - 1) >> BINSHIFT;   // 196

    // workspace carve (256 B aligned)
    char* w = (char*)d_ws;
    auto alloc = [&](size_t bytes) -> void* {
        void* p = (void*)w;
        w += (bytes + 255) & ~(size_t)255;
        return p;
    };
    float* dinv   = (float*)alloc((size_t)N_ * 4);
    int*   hist   = (int*)alloc((size_t)N_ * 4);
    int*   rowptr = (int*)alloc((size_t)(N_ + 1) * 4);
    int*   bsum   = (int*)alloc(512 * 4);
    int*   bbc    = (int*)alloc((size_t)256 * 256 * 4);
    int*   binTotal = (int*)alloc(256 * 4);
    int*   binStart = (int*)alloc(256 * 4);
    int*   ssrc   = (int*)alloc((size_t)E_ * 4);
    unsigned int* binned = (unsigned int*)alloc((size_t)E_ * 4);
    unsigned short* Tb  = (unsigned short*)alloc((size_t)N_ * 64 * 2);
    unsigned short* hBb = (unsigned short*)alloc((size_t)N_ * 64 * 2);
    unsigned short* WT1 = (unsigned short*)alloc((size_t)64 * IND * 2);
    unsigned short* WT2 = (unsigned short*)alloc((size_t)64 * HD * 2);
    unsigned short* WT3 = (unsigned short*)alloc((size_t)64 * HD * 2);
    float* pooled = (float*)alloc((size_t)(NG * 64 + NG) * 4);
    float* gcnt   = pooled + NG * 64;

    const int nchunks = (N_ + SCAN_CHUNK - 1) / SCAN_CHUNK;

    hipMemsetAsync(pooled, 0, (size_t)(NG * 64 + NG) * 4, stream);

    // ---- binned CSR build ----
    binA_kernel<<<PB, 256, 0, stream>>>(dst, bbc, E_, nbins);
    binB1_kernel<<<nbins, 256, 0, stream>>>(bbc, binTotal, binStart);
    scan_bsums_kernel<<<1, 64, 0, stream>>>(binStart, nbins);
    binC_kernel<<<PB, 256, 0, stream>>>(src, dst, bbc, binStart, binned, E_, nbins);
    binH_kernel<<<nbins, 256, 0, stream>>>(binned, binStart, binTotal, hist, dinv, N_);
    scan_sum_kernel<<<nchunks, 256, 0, stream>>>(hist, bsum, N_);
    scan_bsums_kernel<<<1, 64, 0, stream>>>(bsum, nchunks);
    scan_write_kernel<<<nchunks, 256, 0, stream>>>(hist, bsum, rowptr, N_, E_);
    binD_kernel<<<nbins, 256, 0, stream>>>(binned, binStart, binTotal, hist, rowptr, ssrc, N_);

    // ---- weight transposes (tiny) ----
    cvtWT_kernel<<<(64 * IND + 255) / 256, 256, 0, stream>>>(W1, WT1, IND);
    cvtWT_kernel<<<(64 * HD + 255) / 256, 256, 0, stream>>>(W2, WT2, HD);
    cvtWT_kernel<<<(64 * HD + 255) / 256, 256, 0, stream>>>(W3, WT3, HD);

    const int mmblk = (N_ + 63) / 64;             // 64 nodes per block (4 waves x 16)
    const int aggblk = (N_ + 3) / 4;              // 4 waves (nodes) per block

    // layer 1: t = x @ W1 ; h = agg(t) + b1, relu
    mm_mfma_kernel<IND, false><<<mmblk, 256, 0, stream>>>(x, WT1, Tb, N_);
    agg_kernel<<<aggblk, 256, 0, stream>>>(Tb, rowptr, ssrc, dinv, b1, hBb, N_);
    // layer 2
    mm_mfma_kernel<HD, true><<<mmblk, 256, 0, stream>>>(hBb, WT2, Tb, N_);
    agg_kernel<<<aggblk, 256, 0, stream>>>(Tb, rowptr, ssrc, dinv, b2, hBb, N_);
    // layer 3
    mm_mfma_kernel<HD, true><<<mmblk, 256, 0, stream>>>(hBb, WT3, Tb, N_);
    agg_kernel<<<aggblk, 256, 0, stream>>>(Tb, rowptr, ssrc, dinv, b3, hBb, N_);

    // pool + head
    pool_kernel<<<256, 256, 0, stream>>>(hBb, batch, pooled, gcnt, N_);
    head_kernel<<<1, 256, 0, stream>>>(pooled, gcnt, Wm1, bm1, Wm2, bm2, (float*)d_out);
}